// Round 1
// baseline (571.990 us; speedup 1.0000x reference)
//
#include <hip/hip_runtime.h>

#define D_DIM 128
#define NEG_SLOPE 0.2f
#define UNROLL 4   // row-groups per block: 256 threads -> 8 rows/group -> 32 rows/block

typedef float f4 __attribute__((ext_vector_type(4)));

// Layout: 32 lanes per row, each lane owns one float4 of the row from each matrix.
// A wave (64 lanes) covers 2 adjacent rows -> fully coalesced 1KB reads.
// Each thread services UNROLL row-groups; all 2*UNROLL independent loads are
// issued before any reduction so 128B/thread of matrix traffic is in flight
// (8KB/wave, 4x the previous kernel) -> latency hiding via MLP, not just TLP.
__global__ __launch_bounds__(256) void gat_score_kernel(
    const float* __restrict__ Wx_i,
    const float* __restrict__ Wx_j,
    const float* __restrict__ a,
    float* __restrict__ out,
    int E)
{
    const int tid = threadIdx.x;
    const int lane32 = tid & 31;          // float4 slot within the row
    const int rowSlot = tid >> 5;         // 0..7
    const int rowsPerBlock = 8 * UNROLL;  // 32
    const int row0 = blockIdx.x * rowsPerBlock + rowSlot;

    // Attention vector: 1KB total, cache-resident; normal (cached) loads.
    const f4 as = ((const f4*)a)[lane32];
    const f4 ad = ((const f4*)(a + D_DIM))[lane32];

    if (row0 + 8 * (UNROLL - 1) < E) {
        // ---- fast path: all UNROLL rows valid (always taken for E % 32 == 0) ----
        f4 xi[UNROLL], xj[UNROLL];
        #pragma unroll
        for (int k = 0; k < UNROLL; ++k) {
            const size_t base = (size_t)(row0 + 8 * k) * D_DIM;
            // Streamed once, never reused: nontemporal to keep caches for `a`.
            xi[k] = __builtin_nontemporal_load((const f4*)(Wx_i + base) + lane32);
            xj[k] = __builtin_nontemporal_load((const f4*)(Wx_j + base) + lane32);
        }
        #pragma unroll
        for (int k = 0; k < UNROLL; ++k) {
            float s = xi[k].x * as.x + xi[k].y * as.y + xi[k].z * as.z + xi[k].w * as.w
                    + xj[k].x * ad.x + xj[k].y * ad.y + xj[k].z * ad.z + xj[k].w * ad.w;
            #pragma unroll
            for (int off = 16; off > 0; off >>= 1)
                s += __shfl_down(s, off, 32);
            if (lane32 == 0) {
                const int row = row0 + 8 * k;
                out[row] = (s > 0.0f) ? s : NEG_SLOPE * s;
            }
        }
    } else {
        // ---- tail path: per-row guard ----
        for (int k = 0; k < UNROLL; ++k) {
            const int row = row0 + 8 * k;
            if (row < E) {
                const size_t base = (size_t)row * D_DIM;
                const f4 xi = ((const f4*)(Wx_i + base))[lane32];
                const f4 xj = ((const f4*)(Wx_j + base))[lane32];
                float s = xi.x * as.x + xi.y * as.y + xi.z * as.z + xi.w * as.w
                        + xj.x * ad.x + xj.y * ad.y + xj.z * ad.z + xj.w * ad.w;
                #pragma unroll
                for (int off = 16; off > 0; off >>= 1)
                    s += __shfl_down(s, off, 32);
                if (lane32 == 0)
                    out[row] = (s > 0.0f) ? s : NEG_SLOPE * s;
            }
        }
    }
}

extern "C" void kernel_launch(void* const* d_in, const int* in_sizes, int n_in,
                              void* d_out, int out_size, void* d_ws, size_t ws_size,
                              hipStream_t stream) {
    const float* Wx_i = (const float*)d_in[0];
    const float* Wx_j = (const float*)d_in[1];
    const float* a    = (const float*)d_in[2];
    float* out = (float*)d_out;

    const int E = out_size;                    // 640000 rows
    const int rowsPerBlock = 8 * UNROLL;       // 32
    const int grid = (E + rowsPerBlock - 1) / rowsPerBlock;

    gat_score_kernel<<<grid, 256, 0, stream>>>(Wx_i, Wx_j, a, out, E);
}